// Round 7
// baseline (156.488 us; speedup 1.0000x reference)
//
#include <hip/hip_runtime.h>

// Encoder: per-atom top-T nearest grid points -> sum_t rbf[33] (x) (sh[9]*n*w)
// Insight: envelope==0 for d2>=CUTOFF^2, so only in-cutoff points matter.
// K0 zero      : ghist+ghist2+out
// K1 hist_store: ONE full scan; coarse hist of in-cutoff d2 bits + store
//                (bits,idx) pairs per (atom,slice)
// K2 scan1     : per-atom (A blocks): LDS-stage hist, find b1 + residual R2
// K3 fine      : bin crossing-bin pairs into ghist2 (CHF chunks/segment)
// K4 scan2     : per-atom: LDS-stage ghist2, find final 32-ULP threshold
// K5 accum     : filter stored pairs by thr[a], bf16 MFMA (CHA chunks/segment
//                -- R6 lesson: per-atom counts vary ~60k..0, chunking kills
//                the CU-serialization tail that capped occupancy at 17%)

typedef float f32x4 __attribute__((ext_vector_type(4)));
typedef int   i32x4 __attribute__((ext_vector_type(4)));

#define SLICES 16
#define HBINS  8192
#define CHA    4             // accum chunks per segment
#define CHF    4             // fine chunks per segment
#define CUT25  0x41C80000u   // __float_as_uint(25.0f) == CUTOFF^2 bits

__device__ __forceinline__ unsigned d2bits(float px, float py, float pz,
                                           float gx, float gy, float gz) {
  float dx = px - gx, dy = py - gy, dz = pz - gz;
  float d2 = __fmaf_rn(dx, dx, __fmaf_rn(dy, dy, __fmul_rn(dz, dz)));
  return __float_as_uint(d2);
}

__device__ __forceinline__ unsigned short tobf(float v) {
  return (unsigned short)((__float_as_uint(v) + 0x8000u) >> 16);
}

__device__ __forceinline__ void mfma_acc(f32x4& d, i32x4 a, i32x4 b) {
  asm("v_mfma_f32_16x16x32_bf16 %0, %1, %2, %0" : "+v"(d) : "v"(a), "v"(b));
}

// lanes 0..63 walk hist (LDS) for crossing of rank R. Caller pre-inits
// *o_bin = HBINS-1, *o_pre = 0 (defaults when R > total) and syncs after.
__device__ __forceinline__ void scan_find(const unsigned* hist, unsigned R,
                                          unsigned* o_bin, unsigned* o_pre) {
  if (threadIdx.x < 64) {
    int lane = threadIdx.x;
    const int per = HBINS >> 6;
    int base = lane * per;
    unsigned ssum = 0;
    #pragma unroll 8
    for (int k = 0; k < per; ++k) ssum += hist[base + k];
    unsigned p = ssum;
    #pragma unroll
    for (int d = 1; d < 64; d <<= 1) {
      unsigned t = __shfl_up(p, d);
      if (lane >= d) p += t;
    }
    unsigned excl = p - ssum;
    if (excl < R && R <= excl + ssum) {       // unique crossing lane
      unsigned cum = excl;
      for (int k = 0; k < per; ++k) {
        unsigned h = hist[base + k];
        if (cum + h >= R) { *o_bin = (unsigned)(base + k); *o_pre = cum; break; }
        cum += h;
      }
    }
  }
}

// ---------------- K0: zero ghist+ghist2 (contiguous) + out ----------------
__global__ __launch_bounds__(256) void enc_zero(
    i32x4* __restrict__ gh, int nh4, float* __restrict__ ob, int no) {
  int i = blockIdx.x * 256 + threadIdx.x;
  int stride = gridDim.x * 256;
  i32x4 z = {0, 0, 0, 0};
  for (int t = i; t < nh4; t += stride) gh[t] = z;
  for (int t = i; t < no; t += stride) ob[t] = 0.0f;
}

// ---------------- K1: one full scan -> coarse hist + stored pairs ----------------
__global__ __launch_bounds__(256) void enc_hist_store(
    const float* __restrict__ nuc, const float* __restrict__ grid, int N,
    unsigned* __restrict__ ghist, unsigned* __restrict__ cnt,
    uint2* __restrict__ pairs, int scap) {
  __shared__ unsigned lh[HBINS];
  __shared__ unsigned s_cnt;
  int a = blockIdx.x / SLICES, s = blockIdx.x % SLICES;
  for (int t = threadIdx.x; t < HBINS; t += 256) lh[t] = 0;
  if (threadIdx.x == 0) s_cnt = 0;
  __syncthreads();

  float px = nuc[3*a+0], py = nuc[3*a+1], pz = nuc[3*a+2];
  int per = (N + SLICES - 1) / SLICES;
  int lo = s * per, hi = min(N, lo + per);
  int lane = threadIdx.x & 63;
  uint2* seg = pairs + (size_t)(a * SLICES + s) * scap;

  for (int i = lo + threadIdx.x; i < hi; i += 256) {
    float gx = grid[3*i+0], gy = grid[3*i+1], gz = grid[3*i+2];
    unsigned bits = d2bits(px, py, pz, gx, gy, gz);
    bool sel = bits < CUT25;                      // envelope != 0 only here
    if (sel) atomicAdd(&lh[bits >> 18], 1u);
    unsigned long long mm = __ballot(sel);
    if (mm) {
      int leader = __ffsll(mm) - 1;
      unsigned base = 0;
      if (lane == leader) base = atomicAdd(&s_cnt, (unsigned)__popcll(mm));
      base = __shfl(base, leader);
      if (sel) {
        unsigned pos = base + (unsigned)__popcll(mm & ((1ull << lane) - 1ull));
        if (pos < (unsigned)scap) seg[pos] = make_uint2(bits, (unsigned)i);
      }
    }
  }
  __syncthreads();
  unsigned* gh = ghist + (size_t)a * HBINS;
  for (int t = threadIdx.x; t < HBINS; t += 256) {
    unsigned v = lh[t];
    if (v) atomicAdd(&gh[t], v);
  }
  if (threadIdx.x == 0) cnt[a * SLICES + s] = s_cnt;
}

// ---------------- K2: per-atom coarse scan (LDS-staged) ----------------
__global__ __launch_bounds__(256) void enc_scan1(
    const unsigned* __restrict__ ghist, unsigned T,
    unsigned* __restrict__ b1r, unsigned* __restrict__ r2r) {
  __shared__ unsigned lh[HBINS];
  __shared__ unsigned s_bin, s_pre;
  int a = blockIdx.x;
  const i32x4* gh = (const i32x4*)(ghist + (size_t)a * HBINS);
  for (int t = threadIdx.x; t < HBINS / 4; t += 256) ((i32x4*)lh)[t] = gh[t];
  if (threadIdx.x == 0) { s_bin = HBINS - 1; s_pre = 0; }
  __syncthreads();
  scan_find(lh, T, &s_bin, &s_pre);
  __syncthreads();
  if (threadIdx.x == 0) { b1r[a] = s_bin; r2r[a] = T - s_pre; }
}

// ---------------- K3: fine hist of crossing-bin pairs (chunked) ----------------
__global__ __launch_bounds__(256) void enc_fine(
    const unsigned* __restrict__ b1r, const unsigned* __restrict__ cnt,
    const uint2* __restrict__ pairs, int scap, unsigned* __restrict__ ghist2) {
  int seg_id = blockIdx.x / CHF, c = blockIdx.x % CHF;
  int a = seg_id / SLICES;
  unsigned b1 = b1r[a];
  int total = min((int)cnt[seg_id], scap);
  const uint2* seg = pairs + (size_t)seg_id * scap;
  unsigned* gh2 = ghist2 + (size_t)a * HBINS;
  for (int i = c * 256 + threadIdx.x; i < total; i += CHF * 256) {
    uint2 p = seg[i];
    if ((p.x >> 18) == b1) atomicAdd(&gh2[(p.x >> 5) & (HBINS - 1)], 1u);
  }
}

// ---------------- K4: per-atom fine scan -> final threshold ----------------
__global__ __launch_bounds__(256) void enc_scan2(
    const unsigned* __restrict__ ghist2, const unsigned* __restrict__ b1r,
    const unsigned* __restrict__ r2r, unsigned* __restrict__ thr) {
  __shared__ unsigned lh[HBINS];
  __shared__ unsigned s_bin, s_pre;
  int a = blockIdx.x;
  const i32x4* gh = (const i32x4*)(ghist2 + (size_t)a * HBINS);
  for (int t = threadIdx.x; t < HBINS / 4; t += 256) ((i32x4*)lh)[t] = gh[t];
  if (threadIdx.x == 0) { s_bin = HBINS - 1; s_pre = 0; }
  __syncthreads();
  scan_find(lh, r2r[a], &s_bin, &s_pre);
  __syncthreads();
  if (threadIdx.x == 0) thr[a] = (b1r[a] << 13) | s_bin;  // select (bits>>5) <= thr
}

// ---------------- K5: MFMA accumulation over stored pairs (chunked) ----------------
__global__ __launch_bounds__(256, 4) void enc_accum(
    const float* __restrict__ nuc, const float* __restrict__ grid,
    const float* __restrict__ wv, const float* __restrict__ nv,
    const unsigned* __restrict__ thrv, const unsigned* __restrict__ cnt,
    const uint2* __restrict__ pairs, int scap, float* __restrict__ out) {
  __shared__ __align__(16) unsigned short lds[4][4608];  // per-wave 3456 A + 1152 B
  int seg_id = blockIdx.x / CHA, c = blockIdx.x % CHA;
  int a = seg_id / SLICES;
  int tid = threadIdx.x, lane = tid & 63, w = tid >> 6;
  unsigned short* SB = &lds[w][0];

  { // zero this wave's LDS region (covers A pad rows 33..47, B rows 9..15)
    i32x4 z = {0, 0, 0, 0};
    i32x4* zp = (i32x4*)SB;
    #pragma unroll
    for (int t = 0; t < 9; ++t) zp[lane + t * 64] = z;
  }

  unsigned thr = thrv[a];
  float px = nuc[3*a+0], py = nuc[3*a+1], pz = nuc[3*a+2];
  int total = min((int)cnt[seg_id], scap);
  const uint2* lst = pairs + (size_t)seg_id * scap;

  f32x4 acc0 = {0,0,0,0}, acc1 = {0,0,0,0}, acc2 = {0,0,0,0};
  int m = lane & 15, q = lane >> 4;
  const float SQRT2 = 1.41421356237309515f;
  const float PIF   = 3.14159265358979323846f;
  const float S3    = 1.73205080756887729f;

  for (int jb = c * 256 + w * 64; jb < total; jb += CHA * 256) {
    int j = jb + lane;
    bool valid = j < total;
    uint2 pr = valid ? lst[j] : make_uint2(0xFFFFFFFFu, 0u);
    bool live = valid && ((pr.x >> 5) <= thr);   // stored => d2 < 25 => rn < 1
    unsigned gi = pr.y;
    if (live) {
      float gx = grid[3*gi+0], gy = grid[3*gi+1], gz = grid[3*gi+2];
      float dx = px - gx, dy = py - gy, dz = pz - gz;
      float d2 = __fmaf_rn(dx, dx, __fmaf_rn(dy, dy, dz * dz));
      // approx sqrt/rcp (v_sqrt/v_rcp, ~1e-7 rel err << bf16 2^-8)
#if __has_builtin(__builtin_amdgcn_sqrtf)
      float rn = __builtin_amdgcn_sqrtf(d2) * 0.2f;
#else
      float rn = sqrtf(d2) * 0.2f;
#endif
      float x2 = rn * rn;
      float x6 = x2 * x2 * x2;
      float e  = __fmaf_rn(x6, __fmaf_rn(-21.f, x2, __fmaf_rn(48.f, rn, -28.f)), 1.f);
      float f  = SQRT2 * e;
      float nw = nv[gi] * wv[gi];
#if __has_builtin(__builtin_amdgcn_rcpf)
      float inv = 0.2f * __builtin_amdgcn_rcpf(rn + 1e-15f);
#else
      float inv = 0.2f / (rn + 1e-15f);
#endif
      float X = dx * inv, Y = dy * inv, Z = dz * inv;
      float r2 = __fmaf_rn(X, X, __fmaf_rn(Y, Y, Z * Z));
      // B rows: v[h] = nw * sh[h]
      SB[3456 + 0*72 + lane] = tobf(nw);
      SB[3456 + 1*72 + lane] = tobf(nw * Y);
      SB[3456 + 2*72 + lane] = tobf(nw * Z);
      SB[3456 + 3*72 + lane] = tobf(nw * X);
      SB[3456 + 4*72 + lane] = tobf(nw * S3 * X * Y);
      SB[3456 + 5*72 + lane] = tobf(nw * S3 * Y * Z);
      SB[3456 + 6*72 + lane] = tobf(nw * 0.5f * __fmaf_rn(3.f, Z * Z, -r2));
      SB[3456 + 7*72 + lane] = tobf(nw * S3 * X * Z);
      SB[3456 + 8*72 + lane] = tobf(nw * 0.5f * S3 * (X * X - Y * Y));
      // A rows: rbf[r] = sqrt2*e*[0.1, sin(k pi r), cos(k pi r)]
      float s1 = __sinf(PIF * rn), c1 = __cosf(PIF * rn);
      SB[0 * 72 + lane]  = tobf(0.1f * f);
      float sk = s1, ck = c1;
      SB[1 * 72 + lane]  = tobf(f * sk);
      SB[17 * 72 + lane] = tobf(f * ck);
      #pragma unroll
      for (int k = 2; k <= 16; ++k) {
        float sn = __fmaf_rn(sk, c1, ck * s1);
        float cn = __fmaf_rn(ck, c1, -(sk * s1));
        sk = sn; ck = cn;
        SB[k * 72 + lane]        = tobf(f * sk);
        SB[(16 + k) * 72 + lane] = tobf(f * ck);
      }
    } else {
      // zero B column -> this point contributes nothing (A may be stale)
      #pragma unroll
      for (int h = 0; h < 9; ++h) SB[3456 + h * 72 + lane] = 0;
    }
    // MFMA: A[m=r][k=p], B[k=p][n=h]; lane m=l&15, k=8*(l>>4)+j (+32 per k-group)
    #pragma unroll
    for (int g = 0; g < 2; ++g) {
      int cb = 8 * q + 32 * g;
      i32x4 bf = *(const i32x4*)&SB[3456 + m * 72 + cb];
      i32x4 a0 = *(const i32x4*)&SB[(0  + m) * 72 + cb];
      mfma_acc(acc0, a0, bf);
      i32x4 a1 = *(const i32x4*)&SB[(16 + m) * 72 + cb];
      mfma_acc(acc1, a1, bf);
      i32x4 a2 = *(const i32x4*)&SB[(32 + m) * 72 + cb];
      mfma_acc(acc2, a2, bf);
    }
  }
  // MFMA -> VALU read hazard guard
  asm volatile("s_nop 7\n\ts_nop 7" : "+v"(acc0), "+v"(acc1), "+v"(acc2));
  float* op = out + (size_t)a * 297;
  if (m < 9) {
    #pragma unroll
    for (int t = 0; t < 4; ++t) {
      int row = 4 * q + t;                 // C/D: col=lane&15, row=(lane>>4)*4+t
      atomicAdd(&op[(row +  0) * 9 + m], acc0[t]);
      atomicAdd(&op[(row + 16) * 9 + m], acc1[t]);
      if (row + 32 < 33) atomicAdd(&op[(row + 32) * 9 + m], acc2[t]);
    }
  }
}

extern "C" void kernel_launch(void* const* d_in, const int* in_sizes, int n_in,
                              void* d_out, int out_size, void* d_ws, size_t ws_size,
                              hipStream_t stream) {
  const float* nuc  = (const float*)d_in[0];
  // d_in[1] = atom_mask (unused by reference math)
  const float* grid = (const float*)d_in[2];
  const float* wts  = (const float*)d_in[3];
  const float* nn   = (const float*)d_in[4];
  int A = in_sizes[0] / 3;
  int N = in_sizes[2] / 3;
  long long t8 = (8LL * (long long)N) / (long long)A;
  unsigned T = (unsigned)(t8 < (long long)N ? t8 : (long long)N);

  // ws layout: [cnt A*SLICES][b1 A][r2 A][thr A][ghist A*HBINS][ghist2 A*HBINS][pairs]
  unsigned* ws     = (unsigned*)d_ws;
  unsigned* cnt    = ws;
  unsigned* b1r    = cnt + A * SLICES;
  unsigned* r2r    = b1r + A;
  unsigned* thr    = r2r + A;
  unsigned* ghist  = thr + A;
  unsigned* ghist2 = ghist + (size_t)A * HBINS;
  uint2*    pairs  = (uint2*)(ghist2 + (size_t)A * HBINS);

  // per-slice scan range bounds the stored count -> overflow impossible
  int SCAP = (N + SLICES - 1) / SLICES;
  {
    long long head  = (long long)(((unsigned*)pairs) - ws);    // dwords
    long long avail = (long long)(ws_size / 4) - head;         // dwords
    long long need  = 2LL * SCAP * A * SLICES;                 // uint2 = 2 dwords
    if (avail > 0 && need > avail) SCAP = (int)(avail / (2LL * A * SLICES));
  }
  float* out = (float*)d_out;

  int nh4 = (2 * A * HBINS) / 4;   // ghist + ghist2 contiguous
  enc_zero      <<<512,              256, 0, stream>>>((i32x4*)ghist, nh4, out, out_size);
  enc_hist_store<<<A * SLICES,       256, 0, stream>>>(nuc, grid, N, ghist, cnt, pairs, SCAP);
  enc_scan1     <<<A,                256, 0, stream>>>(ghist, T, b1r, r2r);
  enc_fine      <<<A * SLICES * CHF, 256, 0, stream>>>(b1r, cnt, pairs, SCAP, ghist2);
  enc_scan2     <<<A,                256, 0, stream>>>(ghist2, b1r, r2r, thr);
  enc_accum     <<<A * SLICES * CHA, 256, 0, stream>>>(nuc, grid, wts, nn, thr, cnt,
                                                       pairs, SCAP, out);
}

// Round 8
// 98.730 us; speedup vs baseline: 1.5850x; 1.5850x over previous
//
#include <hip/hip_runtime.h>

// Encoder: per-atom top-T nearest grid points -> sum_t rbf[33] (x) (sh[9]*n*w)
// K0 zero      : ghist+ghist2
// K1 hist_store: ONE full scan; coarse hist of in-cutoff d2 bits + store
//                (bits,idx) pairs per (atom,slice)
// K2 scan1     : per-atom: LDS-stage hist, find b1 + residual R2
// K3 fine      : bin crossing-bin pairs into ghist2 (CHF chunks/segment)
// K4 scan2     : per-atom: LDS-stage ghist2, find final 32-ULP threshold
// K5 accum     : filter pairs by thr[a], bf16 MFMA, cross-wave LDS reduce,
//                ONE plain store of 297 partials per block (R7 lesson:
//                4.9M same-line global atomics in the epilogue = 97us)
// K6 reduce    : sum 64 chunk-partials per atom -> out (plain stores)

typedef float f32x4 __attribute__((ext_vector_type(4)));
typedef int   i32x4 __attribute__((ext_vector_type(4)));

#define SLICES 16
#define HBINS  8192
#define CHA    4             // accum chunks per segment
#define CHF    4             // fine chunks per segment
#define NCHUNK (SLICES * CHA)
#define PBSTR  304           // partials row stride (297 rounded to 16B mult)
#define CUT25  0x41C80000u   // __float_as_uint(25.0f) == CUTOFF^2 bits

__device__ __forceinline__ unsigned d2bits(float px, float py, float pz,
                                           float gx, float gy, float gz) {
  float dx = px - gx, dy = py - gy, dz = pz - gz;
  float d2 = __fmaf_rn(dx, dx, __fmaf_rn(dy, dy, __fmul_rn(dz, dz)));
  return __float_as_uint(d2);
}

__device__ __forceinline__ unsigned short tobf(float v) {
  return (unsigned short)((__float_as_uint(v) + 0x8000u) >> 16);
}

__device__ __forceinline__ void mfma_acc(f32x4& d, i32x4 a, i32x4 b) {
  asm("v_mfma_f32_16x16x32_bf16 %0, %1, %2, %0" : "+v"(d) : "v"(a), "v"(b));
}

// lanes 0..63 walk hist (LDS) for crossing of rank R. Caller pre-inits
// *o_bin = HBINS-1, *o_pre = 0 (defaults when R > total) and syncs after.
__device__ __forceinline__ void scan_find(const unsigned* hist, unsigned R,
                                          unsigned* o_bin, unsigned* o_pre) {
  if (threadIdx.x < 64) {
    int lane = threadIdx.x;
    const int per = HBINS >> 6;
    int base = lane * per;
    unsigned ssum = 0;
    #pragma unroll 8
    for (int k = 0; k < per; ++k) ssum += hist[base + k];
    unsigned p = ssum;
    #pragma unroll
    for (int d = 1; d < 64; d <<= 1) {
      unsigned t = __shfl_up(p, d);
      if (lane >= d) p += t;
    }
    unsigned excl = p - ssum;
    if (excl < R && R <= excl + ssum) {       // unique crossing lane
      unsigned cum = excl;
      for (int k = 0; k < per; ++k) {
        unsigned h = hist[base + k];
        if (cum + h >= R) { *o_bin = (unsigned)(base + k); *o_pre = cum; break; }
        cum += h;
      }
    }
  }
}

// ---------------- K0: zero ghist+ghist2 (contiguous) ----------------
__global__ __launch_bounds__(256) void enc_zero(
    i32x4* __restrict__ gh, int nh4) {
  int i = blockIdx.x * 256 + threadIdx.x;
  int stride = gridDim.x * 256;
  i32x4 z = {0, 0, 0, 0};
  for (int t = i; t < nh4; t += stride) gh[t] = z;
}

// ---------------- K1: one full scan -> coarse hist + stored pairs ----------------
__global__ __launch_bounds__(256) void enc_hist_store(
    const float* __restrict__ nuc, const float* __restrict__ grid, int N,
    unsigned* __restrict__ ghist, unsigned* __restrict__ cnt,
    uint2* __restrict__ pairs, int scap) {
  __shared__ unsigned lh[HBINS];
  __shared__ unsigned s_cnt;
  int a = blockIdx.x / SLICES, s = blockIdx.x % SLICES;
  for (int t = threadIdx.x; t < HBINS; t += 256) lh[t] = 0;
  if (threadIdx.x == 0) s_cnt = 0;
  __syncthreads();

  float px = nuc[3*a+0], py = nuc[3*a+1], pz = nuc[3*a+2];
  int per = (N + SLICES - 1) / SLICES;
  int lo = s * per, hi = min(N, lo + per);
  int lane = threadIdx.x & 63;
  uint2* seg = pairs + (size_t)(a * SLICES + s) * scap;

  for (int i = lo + threadIdx.x; i < hi; i += 256) {
    float gx = grid[3*i+0], gy = grid[3*i+1], gz = grid[3*i+2];
    unsigned bits = d2bits(px, py, pz, gx, gy, gz);
    bool sel = bits < CUT25;                      // envelope != 0 only here
    if (sel) atomicAdd(&lh[bits >> 18], 1u);
    unsigned long long mm = __ballot(sel);
    if (mm) {
      int leader = __ffsll(mm) - 1;
      unsigned base = 0;
      if (lane == leader) base = atomicAdd(&s_cnt, (unsigned)__popcll(mm));
      base = __shfl(base, leader);
      if (sel) {
        unsigned pos = base + (unsigned)__popcll(mm & ((1ull << lane) - 1ull));
        if (pos < (unsigned)scap) seg[pos] = make_uint2(bits, (unsigned)i);
      }
    }
  }
  __syncthreads();
  unsigned* gh = ghist + (size_t)a * HBINS;
  for (int t = threadIdx.x; t < HBINS; t += 256) {
    unsigned v = lh[t];
    if (v) atomicAdd(&gh[t], v);
  }
  if (threadIdx.x == 0) cnt[a * SLICES + s] = s_cnt;
}

// ---------------- K2: per-atom coarse scan (LDS-staged) ----------------
__global__ __launch_bounds__(256) void enc_scan1(
    const unsigned* __restrict__ ghist, unsigned T,
    unsigned* __restrict__ b1r, unsigned* __restrict__ r2r) {
  __shared__ unsigned lh[HBINS];
  __shared__ unsigned s_bin, s_pre;
  int a = blockIdx.x;
  const i32x4* gh = (const i32x4*)(ghist + (size_t)a * HBINS);
  for (int t = threadIdx.x; t < HBINS / 4; t += 256) ((i32x4*)lh)[t] = gh[t];
  if (threadIdx.x == 0) { s_bin = HBINS - 1; s_pre = 0; }
  __syncthreads();
  scan_find(lh, T, &s_bin, &s_pre);
  __syncthreads();
  if (threadIdx.x == 0) { b1r[a] = s_bin; r2r[a] = T - s_pre; }
}

// ---------------- K3: fine hist of crossing-bin pairs (chunked) ----------------
__global__ __launch_bounds__(256) void enc_fine(
    const unsigned* __restrict__ b1r, const unsigned* __restrict__ cnt,
    const uint2* __restrict__ pairs, int scap, unsigned* __restrict__ ghist2) {
  int seg_id = blockIdx.x / CHF, c = blockIdx.x % CHF;
  int a = seg_id / SLICES;
  unsigned b1 = b1r[a];
  int total = min((int)cnt[seg_id], scap);
  const uint2* seg = pairs + (size_t)seg_id * scap;
  unsigned* gh2 = ghist2 + (size_t)a * HBINS;
  for (int i = c * 256 + threadIdx.x; i < total; i += CHF * 256) {
    uint2 p = seg[i];
    if ((p.x >> 18) == b1) atomicAdd(&gh2[(p.x >> 5) & (HBINS - 1)], 1u);
  }
}

// ---------------- K4: per-atom fine scan -> final threshold ----------------
__global__ __launch_bounds__(256) void enc_scan2(
    const unsigned* __restrict__ ghist2, const unsigned* __restrict__ b1r,
    const unsigned* __restrict__ r2r, unsigned* __restrict__ thr) {
  __shared__ unsigned lh[HBINS];
  __shared__ unsigned s_bin, s_pre;
  int a = blockIdx.x;
  const i32x4* gh = (const i32x4*)(ghist2 + (size_t)a * HBINS);
  for (int t = threadIdx.x; t < HBINS / 4; t += 256) ((i32x4*)lh)[t] = gh[t];
  if (threadIdx.x == 0) { s_bin = HBINS - 1; s_pre = 0; }
  __syncthreads();
  scan_find(lh, r2r[a], &s_bin, &s_pre);
  __syncthreads();
  if (threadIdx.x == 0) thr[a] = (b1r[a] << 13) | s_bin;  // select (bits>>5) <= thr
}

// ---------------- K5: MFMA accumulation -> per-block partials (no atomics) ----------------
__global__ __launch_bounds__(256, 4) void enc_accum(
    const float* __restrict__ nuc, const float* __restrict__ grid,
    const float* __restrict__ wv, const float* __restrict__ nv,
    const unsigned* __restrict__ thrv, const unsigned* __restrict__ cnt,
    const uint2* __restrict__ pairs, int scap, float* __restrict__ pb) {
  __shared__ __align__(16) unsigned short lds[4][4608];  // per-wave 3456 A + 1152 B
  int seg_id = blockIdx.x / CHA, c = blockIdx.x % CHA;
  int a = seg_id / SLICES;
  int tid = threadIdx.x, lane = tid & 63, w = tid >> 6;
  unsigned short* SB = &lds[w][0];

  { // zero this wave's LDS region (covers A pad rows 33..47, B rows 9..15)
    i32x4 z = {0, 0, 0, 0};
    i32x4* zp = (i32x4*)SB;
    #pragma unroll
    for (int t = 0; t < 9; ++t) zp[lane + t * 64] = z;
  }

  unsigned thr = thrv[a];
  float px = nuc[3*a+0], py = nuc[3*a+1], pz = nuc[3*a+2];
  int total = min((int)cnt[seg_id], scap);
  const uint2* lst = pairs + (size_t)seg_id * scap;

  f32x4 acc0 = {0,0,0,0}, acc1 = {0,0,0,0}, acc2 = {0,0,0,0};
  int m = lane & 15, q = lane >> 4;
  const float SQRT2 = 1.41421356237309515f;
  const float PIF   = 3.14159265358979323846f;
  const float S3    = 1.73205080756887729f;

  for (int jb = c * 256 + w * 64; jb < total; jb += CHA * 256) {
    int j = jb + lane;
    bool valid = j < total;
    uint2 pr = valid ? lst[j] : make_uint2(0xFFFFFFFFu, 0u);
    bool live = valid && ((pr.x >> 5) <= thr);   // stored => d2 < 25 => rn < 1
    unsigned gi = pr.y;
    if (live) {
      float gx = grid[3*gi+0], gy = grid[3*gi+1], gz = grid[3*gi+2];
      float dx = px - gx, dy = py - gy, dz = pz - gz;
      float d2 = __fmaf_rn(dx, dx, __fmaf_rn(dy, dy, dz * dz));
#if __has_builtin(__builtin_amdgcn_sqrtf)
      float rn = __builtin_amdgcn_sqrtf(d2) * 0.2f;
#else
      float rn = sqrtf(d2) * 0.2f;
#endif
      float x2 = rn * rn;
      float x6 = x2 * x2 * x2;
      float e  = __fmaf_rn(x6, __fmaf_rn(-21.f, x2, __fmaf_rn(48.f, rn, -28.f)), 1.f);
      float f  = SQRT2 * e;
      float nw = nv[gi] * wv[gi];
#if __has_builtin(__builtin_amdgcn_rcpf)
      float inv = 0.2f * __builtin_amdgcn_rcpf(rn + 1e-15f);
#else
      float inv = 0.2f / (rn + 1e-15f);
#endif
      float X = dx * inv, Y = dy * inv, Z = dz * inv;
      float r2 = __fmaf_rn(X, X, __fmaf_rn(Y, Y, Z * Z));
      // B rows: v[h] = nw * sh[h]
      SB[3456 + 0*72 + lane] = tobf(nw);
      SB[3456 + 1*72 + lane] = tobf(nw * Y);
      SB[3456 + 2*72 + lane] = tobf(nw * Z);
      SB[3456 + 3*72 + lane] = tobf(nw * X);
      SB[3456 + 4*72 + lane] = tobf(nw * S3 * X * Y);
      SB[3456 + 5*72 + lane] = tobf(nw * S3 * Y * Z);
      SB[3456 + 6*72 + lane] = tobf(nw * 0.5f * __fmaf_rn(3.f, Z * Z, -r2));
      SB[3456 + 7*72 + lane] = tobf(nw * S3 * X * Z);
      SB[3456 + 8*72 + lane] = tobf(nw * 0.5f * S3 * (X * X - Y * Y));
      // A rows: rbf[r] = sqrt2*e*[0.1, sin(k pi r), cos(k pi r)]
      float s1 = __sinf(PIF * rn), c1 = __cosf(PIF * rn);
      SB[0 * 72 + lane]  = tobf(0.1f * f);
      float sk = s1, ck = c1;
      SB[1 * 72 + lane]  = tobf(f * sk);
      SB[17 * 72 + lane] = tobf(f * ck);
      #pragma unroll
      for (int k = 2; k <= 16; ++k) {
        float sn = __fmaf_rn(sk, c1, ck * s1);
        float cn = __fmaf_rn(ck, c1, -(sk * s1));
        sk = sn; ck = cn;
        SB[k * 72 + lane]        = tobf(f * sk);
        SB[(16 + k) * 72 + lane] = tobf(f * ck);
      }
    } else {
      // zero B column -> this point contributes nothing (A may be stale)
      #pragma unroll
      for (int h = 0; h < 9; ++h) SB[3456 + h * 72 + lane] = 0;
    }
    // MFMA: A[m=r][k=p], B[k=p][n=h]; lane m=l&15, k=8*(l>>4)+j (+32 per k-group)
    #pragma unroll
    for (int g = 0; g < 2; ++g) {
      int cb = 8 * q + 32 * g;
      i32x4 bf = *(const i32x4*)&SB[3456 + m * 72 + cb];
      i32x4 a0 = *(const i32x4*)&SB[(0  + m) * 72 + cb];
      mfma_acc(acc0, a0, bf);
      i32x4 a1 = *(const i32x4*)&SB[(16 + m) * 72 + cb];
      mfma_acc(acc1, a1, bf);
      i32x4 a2 = *(const i32x4*)&SB[(32 + m) * 72 + cb];
      mfma_acc(acc2, a2, bf);
    }
  }
  // MFMA -> VALU read hazard guard
  asm volatile("s_nop 7\n\ts_nop 7" : "+v"(acc0), "+v"(acc1), "+v"(acc2));

  // cross-wave reduction in LDS (wave-private regions; DS ops in-order per wave)
  float* redw = (float*)&lds[w][0];
  if (m < 9) {
    #pragma unroll
    for (int t = 0; t < 4; ++t) {
      int row = 4 * q + t;                 // C/D: col=lane&15, row=(lane>>4)*4+t
      redw[(row +  0) * 9 + m] = acc0[t];
      redw[(row + 16) * 9 + m] = acc1[t];
      if (row + 32 < 33) redw[(row + 32) * 9 + m] = acc2[t];
    }
  }
  __syncthreads();
  float* pbb = pb + (size_t)blockIdx.x * PBSTR;
  for (int v = tid; v < 297; v += 256) {
    float s0 = ((const float*)&lds[0][0])[v] + ((const float*)&lds[1][0])[v];
    float s1 = ((const float*)&lds[2][0])[v] + ((const float*)&lds[3][0])[v];
    pbb[v] = s0 + s1;                      // plain store -- zero atomics
  }
}

// ---------------- K6: sum chunk partials -> out ----------------
__global__ __launch_bounds__(256) void enc_reduce(
    const float* __restrict__ pb, float* __restrict__ out, int nout) {
  int idx = blockIdx.x * 256 + threadIdx.x;
  if (idx >= nout) return;
  int a = idx / 297, v = idx - a * 297;
  const float* p = pb + (size_t)a * NCHUNK * PBSTR + v;
  float s = 0.f;
  #pragma unroll 8
  for (int k = 0; k < NCHUNK; ++k) s += p[(size_t)k * PBSTR];
  out[idx] = s;
}

extern "C" void kernel_launch(void* const* d_in, const int* in_sizes, int n_in,
                              void* d_out, int out_size, void* d_ws, size_t ws_size,
                              hipStream_t stream) {
  const float* nuc  = (const float*)d_in[0];
  // d_in[1] = atom_mask (unused by reference math)
  const float* grid = (const float*)d_in[2];
  const float* wts  = (const float*)d_in[3];
  const float* nn   = (const float*)d_in[4];
  int A = in_sizes[0] / 3;
  int N = in_sizes[2] / 3;
  long long t8 = (8LL * (long long)N) / (long long)A;
  unsigned T = (unsigned)(t8 < (long long)N ? t8 : (long long)N);

  // ws: [cnt A*SLICES][b1 A][r2 A][thr A][ghist A*HBINS][ghist2 A*HBINS]
  //     [pb A*SLICES*CHA*PBSTR floats][pairs uint2 ...]
  unsigned* ws     = (unsigned*)d_ws;
  unsigned* cnt    = ws;
  unsigned* b1r    = cnt + A * SLICES;
  unsigned* r2r    = b1r + A;
  unsigned* thr    = r2r + A;
  unsigned* ghist  = thr + A;
  unsigned* ghist2 = ghist + (size_t)A * HBINS;
  float*    pb     = (float*)(ghist2 + (size_t)A * HBINS);
  uint2*    pairs  = (uint2*)(pb + (size_t)A * SLICES * CHA * PBSTR);

  // per-slice scan range bounds the stored count -> overflow impossible
  int SCAP = (N + SLICES - 1) / SLICES;
  {
    long long head  = (long long)(((unsigned*)pairs) - ws);    // dwords
    long long avail = (long long)(ws_size / 4) - head;         // dwords
    long long need  = 2LL * SCAP * A * SLICES;                 // uint2 = 2 dwords
    if (avail > 0 && need > avail) SCAP = (int)(avail / (2LL * A * SLICES));
  }
  float* out = (float*)d_out;

  int nh4  = (2 * A * HBINS) / 4;   // ghist + ghist2 contiguous
  int nout = A * 297;
  enc_zero      <<<512,                256, 0, stream>>>((i32x4*)ghist, nh4);
  enc_hist_store<<<A * SLICES,         256, 0, stream>>>(nuc, grid, N, ghist, cnt, pairs, SCAP);
  enc_scan1     <<<A,                  256, 0, stream>>>(ghist, T, b1r, r2r);
  enc_fine      <<<A * SLICES * CHF,   256, 0, stream>>>(b1r, cnt, pairs, SCAP, ghist2);
  enc_scan2     <<<A,                  256, 0, stream>>>(ghist2, b1r, r2r, thr);
  enc_accum     <<<A * SLICES * CHA,   256, 0, stream>>>(nuc, grid, wts, nn, thr, cnt,
                                                         pairs, SCAP, pb);
  enc_reduce    <<<(nout + 255) / 256, 256, 0, stream>>>(pb, out, nout);
}